// Round 3
// baseline (253.927 us; speedup 1.0000x reference)
//
#include <hip/hip_runtime.h>
#include <stdint.h>

#define D 128
#define EPB2 1024  // edges per hist/scat block
#define CSZ 128    // nodes per cluster (cluster = dst >> 7)

typedef __bf16 bf16x8 __attribute__((ext_vector_type(8)));
typedef float f32x4 __attribute__((ext_vector_type(4)));

__device__ inline float bf2f(unsigned short u) {
    return __uint_as_float((unsigned)u << 16);
}
__device__ inline unsigned short f2bf(float f) {
    unsigned u = __float_as_uint(f);
    return (unsigned short)((u + 0x7FFF + ((u >> 16) & 1)) >> 16);  // RNE
}

struct Params {
    const float* x; const int* ei; const float* ew;
    const float* W1; const float* b1; const float* W2; const float* b2;
    float* out;
    int N, E, C, B2n, gb, hb;
    unsigned short *Wt1, *Wt2;
    unsigned int* ctot; int* cbase; unsigned int* gcur;
    float* deg;               // raw degree sums (atomic)
    float* dinv; int* cnt; int* rowstart;
    int2* brec; int2* erec;
    unsigned short *Hbuf, *Abuf;
};

// ================= phase bodies =================

__device__ inline void dev_prep(int which, const Params& p) {
    const float* W = (which == 0) ? p.W1 : p.W2;
    unsigned short* Wt = (which == 0) ? p.Wt1 : p.Wt2;
    for (int i = threadIdx.x; i < 2048; i += 256) {
        int nn = i >> 4;
        int kc = (i & 15) << 3;
        ushort4 o0, o1;
        o0.x = f2bf(W[(kc + 0) * 128 + nn]); o0.y = f2bf(W[(kc + 1) * 128 + nn]);
        o0.z = f2bf(W[(kc + 2) * 128 + nn]); o0.w = f2bf(W[(kc + 3) * 128 + nn]);
        o1.x = f2bf(W[(kc + 4) * 128 + nn]); o1.y = f2bf(W[(kc + 5) * 128 + nn]);
        o1.z = f2bf(W[(kc + 6) * 128 + nn]); o1.w = f2bf(W[(kc + 7) * 128 + nn]);
        *(ushort4*)(Wt + nn * 128 + kc) = o0;
        *(ushort4*)(Wt + nn * 128 + kc + 4) = o1;
    }
}

// hist (cluster counts) + degree accumulation (global float atomics)
__device__ inline void dev_hist2(int b, const Params& p, unsigned int* hist) {
    for (int i = threadIdx.x; i < p.C; i += 256) hist[i] = 0;
    __syncthreads();
    const int base = b * EPB2 + threadIdx.x;
#pragma unroll
    for (int k = 0; k < EPB2 / 256; ++k) {
        int e = base + k * 256;
        if (e < p.E) {
            unsigned d = (unsigned)p.ei[p.E + e];
            atomicAdd(&hist[d >> 7], 1u);
            atomicAdd(&p.deg[d], p.ew[e]);
        }
    }
    __syncthreads();
    for (int i = threadIdx.x; i < p.C; i += 256) {
        unsigned v = hist[i];
        if (v) atomicAdd(&p.ctot[i], v);
    }
}

// single-block exclusive scan of ctot[C] (C <= 512) -> cbase, gcur
__device__ inline void dev_cscan(const Params& p, int* s) {
    const int tid = threadIdx.x;
    const int c0 = tid, c1 = tid + 256;
    s[c0] = (c0 < p.C) ? (int)p.ctot[c0] : 0;
    s[c1] = (c1 < p.C) ? (int)p.ctot[c1] : 0;
    __syncthreads();
    for (int off = 1; off < 512; off <<= 1) {
        int t0 = (c0 >= off) ? s[c0 - off] : 0;
        int t1 = (c1 >= off) ? s[c1 - off] : 0;
        __syncthreads();
        s[c0] += t0; s[c1] += t1;
        __syncthreads();
    }
    if (c0 < p.C) { int b0 = (c0 == 0) ? 0 : s[c0 - 1]; p.cbase[c0] = b0; p.gcur[c0] = (unsigned)b0; }
    if (c1 < p.C) { int b1 = s[c1 - 1]; p.cbase[c1] = b1; p.gcur[c1] = (unsigned)b1; }
    if (tid == 0) p.cbase[p.C] = p.E;
}

// scatter edges into cluster-sorted brec via per-cluster chunk reservation
__device__ inline void dev_scat2(int b, const Params& p, unsigned int* a) {
    unsigned int* hcnt = a;        // [512]
    unsigned int* hcur = a + 512;  // [512]
    const int tid = threadIdx.x;
    for (int i = tid; i < p.C; i += 256) hcnt[i] = 0;
    __syncthreads();
    const int base = b * EPB2 + tid;
#pragma unroll
    for (int k = 0; k < EPB2 / 256; ++k) {
        int e = base + k * 256;
        if (e < p.E) atomicAdd(&hcnt[((unsigned)p.ei[p.E + e]) >> 7], 1u);
    }
    __syncthreads();
    for (int i = tid; i < p.C; i += 256) {
        unsigned c = hcnt[i];
        hcur[i] = c ? atomicAdd(&p.gcur[i], c) : 0u;
    }
    __syncthreads();
#pragma unroll
    for (int k = 0; k < EPB2 / 256; ++k) {
        int e = base + k * 256;
        if (e < p.E) {
            int s = p.ei[e];
            unsigned d = (unsigned)p.ei[p.E + e];
            float w = p.ew[e];
            int c = (int)(d >> 7);
            unsigned r = atomicAdd(&hcur[c], 1u);
            p.brec[r] = make_int2((int)((d << 16) | (unsigned)s), __float_as_int(w));
        }
    }
}

// per-cluster CSR build (counts + reorder only; dinv handled by GEMM1)
__device__ inline void dev_cbuild(int c, const Params& p, unsigned int* a, int cs, int ce) {
    unsigned int* hcnt = a;
    unsigned int* lsc  = a + CSZ;
    unsigned int* curs = a + 2 * CSZ;
    const int tid = threadIdx.x;
    if (tid < CSZ) hcnt[tid] = 0;
    __syncthreads();
    for (int i = cs + tid; i < ce; i += 256) {
        int2 r = p.brec[i];
        int local = (int)(((unsigned)r.x) >> 16) & (CSZ - 1);
        atomicAdd(&hcnt[local], 1u);
    }
    __syncthreads();
    if (tid < CSZ) lsc[tid] = hcnt[tid];
    __syncthreads();
    for (int off = 1; off < CSZ; off <<= 1) {
        unsigned t = (tid < CSZ && tid >= off) ? lsc[tid - off] : 0u;
        __syncthreads();
        if (tid < CSZ) lsc[tid] += t;
        __syncthreads();
    }
    if (tid < CSZ) {
        unsigned excl = lsc[tid] - hcnt[tid];
        curs[tid] = excl;
        int node = c * CSZ + tid;
        if (node < p.N) {
            p.rowstart[node] = cs + (int)excl;
            p.cnt[node] = (int)hcnt[tid];
        }
    }
    __syncthreads();
    for (int i = cs + tid; i < ce; i += 256) {
        int2 r = p.brec[i];
        int local = (int)(((unsigned)r.x) >> 16) & (CSZ - 1);
        unsigned rk = atomicAdd(&curs[local], 1u);
        p.erec[cs + (int)rk] = make_int2(r.x & 0xFFFF, r.y);   // (src, ew)
    }
}

// ---------------- MFMA GEMM body with dinv-scaled epilogue ----------------
// Writes Hs[row] = dinv[row] * (X@W)[row], bf16.
// FROM_DEG: compute dinv = rsqrt(1+deg) here and persist it; else read p.dinv.
template <bool IN_BF16, bool FROM_DEG>
__device__ inline void mfma_sc(unsigned short* sE, const Params& p,
                               const void* __restrict__ Xv,
                               const unsigned short* __restrict__ Wt,
                               unsigned short* __restrict__ H, int n, int blk) {
    const int tid = threadIdx.x;
    const int row0 = blk * 64;
    const int lane = tid & 63;
    const int wv = tid >> 6;
    const int qm = lane & 15;
    const int quad = lane >> 4;

    const int arow = row0 + wv * 16 + qm;
    const int ar = (arow < n) ? arow : (n - 1);

    f32x4 acc[8];
#pragma unroll
    for (int i = 0; i < 8; ++i) acc[i] = (f32x4){0.f, 0.f, 0.f, 0.f};

#pragma unroll
    for (int kb = 0; kb < 4; ++kb) {
        const int koff = kb * 32 + quad * 8;
        bf16x8 a;
        if (IN_BF16) {
            a = *(const bf16x8*)((const unsigned short*)Xv + (size_t)ar * 128 + koff);
        } else {
            const float* Xf = (const float*)Xv + (size_t)ar * 128 + koff;
            float4 v0 = *(const float4*)(Xf);
            float4 v1 = *(const float4*)(Xf + 4);
            union { bf16x8 v; ushort4 u[2]; } cv;
            cv.u[0].x = f2bf(v0.x); cv.u[0].y = f2bf(v0.y);
            cv.u[0].z = f2bf(v0.z); cv.u[0].w = f2bf(v0.w);
            cv.u[1].x = f2bf(v1.x); cv.u[1].y = f2bf(v1.y);
            cv.u[1].z = f2bf(v1.z); cv.u[1].w = f2bf(v1.w);
            a = cv.v;
        }
#pragma unroll
        for (int n0 = 0; n0 < 8; ++n0) {
            bf16x8 b = *(const bf16x8*)(Wt + (n0 * 16 + qm) * 128 + koff);
            acc[n0] = __builtin_amdgcn_mfma_f32_16x16x32_bf16(a, b, acc[n0], 0, 0, 0);
        }
    }

    // per-C-row dinv
    const int crow = wv * 16 + quad * 4;
    float di[4];
#pragma unroll
    for (int r = 0; r < 4; ++r) {
        int rr = row0 + crow + r;
        int rc = (rr < n) ? rr : (n - 1);
        if (FROM_DEG) {
            di[r] = rsqrtf(1.0f + p.deg[rc]);
            if (qm == 0 && rr < n) p.dinv[rr] = di[r];
        } else {
            di[r] = p.dinv[rc];
        }
    }

#pragma unroll
    for (int n0 = 0; n0 < 8; ++n0)
#pragma unroll
        for (int r = 0; r < 4; ++r)
            sE[(crow + r) * 136 + n0 * 16 + qm] = f2bf(acc[n0][r] * di[r]);
    __syncthreads();

    const int row_in = lane >> 2;
    const int c0 = (lane & 3) * 4;
    const int grow = row0 + wv * 16 + row_in;
    if (grow < n) {
#pragma unroll
        for (int j = 0; j < 4; ++j)
            *(int4*)(H + (size_t)grow * 128 + (c0 + j) * 8) =
                *(const int4*)(&sE[(wv * 16 + row_in) * 136 + (c0 + j) * 8]);
    }
}

// ---------------- gather: OUT[d] = act(b + dinv[d]*(Hs[d] + sum ew*Hs[src])) ----------------
// 16 lanes/node, 16B row loads, unroll 4. No dinv[src] loads (folded into Hs).
template <bool OUT_BF16, bool RELU>
__device__ inline void gatherS(const Params& p, const unsigned short* __restrict__ Hs,
                               const float* __restrict__ bias, void* __restrict__ OUTv, int g) {
    const int lane = threadIdx.x & 15;
    const int node = g * 16 + (threadIdx.x >> 4);
    if (node >= p.N) return;
    const int start = p.rowstart[node];
    const int m = p.cnt[node];
    const float di = p.dinv[node];

    const int4* __restrict__ H4 = (const int4*)Hs;  // 16 int4 per row
    union U8 { int4 v; unsigned short u[8]; };
    U8 s; s.v = H4[(size_t)node * 16 + lane];
    float acc[8];
#pragma unroll
    for (int q = 0; q < 8; ++q) acc[q] = bf2f(s.u[q]);   // self term: Hs[d]

    const int2* __restrict__ er = p.erec + start;
    int j = 0;
    for (; j + 4 <= m; j += 4) {
        int2 e0 = er[j], e1 = er[j + 1], e2 = er[j + 2], e3 = er[j + 3];
        U8 v0, v1, v2, v3;
        v0.v = H4[(size_t)e0.x * 16 + lane];
        v1.v = H4[(size_t)e1.x * 16 + lane];
        v2.v = H4[(size_t)e2.x * 16 + lane];
        v3.v = H4[(size_t)e3.x * 16 + lane];
        float w0 = __int_as_float(e0.y), w1 = __int_as_float(e1.y);
        float w2 = __int_as_float(e2.y), w3 = __int_as_float(e3.y);
#pragma unroll
        for (int q = 0; q < 8; ++q)
            acc[q] += w0 * bf2f(v0.u[q]) + w1 * bf2f(v1.u[q]) +
                      w2 * bf2f(v2.u[q]) + w3 * bf2f(v3.u[q]);
    }
    for (; j < m; ++j) {
        int2 e0 = er[j];
        U8 v0; v0.v = H4[(size_t)e0.x * 16 + lane];
        float w0 = __int_as_float(e0.y);
#pragma unroll
        for (int q = 0; q < 8; ++q) acc[q] += w0 * bf2f(v0.u[q]);
    }

    const float4 b0 = *(const float4*)(bias + lane * 8);
    const float4 b1 = *(const float4*)(bias + lane * 8 + 4);
    float o[8] = {b0.x, b0.y, b0.z, b0.w, b1.x, b1.y, b1.z, b1.w};
#pragma unroll
    for (int q = 0; q < 8; ++q) {
        float v = o[q] + di * acc[q];
        if (RELU) v = fmaxf(v, 0.f);
        o[q] = v;
    }
    if (OUT_BF16) {
        U8 ov;
#pragma unroll
        for (int q = 0; q < 8; ++q) ov.u[q] = f2bf(o[q]);
        ((int4*)OUTv)[(size_t)node * 16 + lane] = ov.v;
    } else {
        float4 f0 = {o[0], o[1], o[2], o[3]};
        float4 f1 = {o[4], o[5], o[6], o[7]};
        float4* O = (float4*)OUTv;
        O[(size_t)node * 32 + lane * 2] = f0;
        O[(size_t)node * 32 + lane * 2 + 1] = f1;
    }
}

// ================= 7-kernel pipeline =================
__global__ __launch_bounds__(256, 4) void k_b0(Params p) {   // prep + hist + deg
    __shared__ __align__(16) unsigned int hist[512];
    if (blockIdx.x < 2) dev_prep(blockIdx.x, p);
    else dev_hist2(blockIdx.x - 2, p, hist);
}
__global__ __launch_bounds__(256, 4) void k_b1(Params p) {   // GEMM1 (deg->dinv, Hs1) + cscan
    __shared__ __align__(16) char arena[64 * 136 * 2];
    if ((int)blockIdx.x < p.gb)
        mfma_sc<false, true>((unsigned short*)arena, p, (const void*)p.x, p.Wt1, p.Hbuf, p.N, blockIdx.x);
    else
        dev_cscan(p, (int*)arena);
}
__global__ __launch_bounds__(256) void k_b2(Params p) {      // scatter
    __shared__ unsigned int a[1024];
    dev_scat2(blockIdx.x, p, a);
}
__global__ __launch_bounds__(256) void k_b3(Params p) {      // CSR build
    __shared__ unsigned int a[3 * CSZ];
    dev_cbuild(blockIdx.x, p, a, p.cbase[blockIdx.x], p.cbase[blockIdx.x + 1]);
}
__global__ __launch_bounds__(256) void k_b4(Params p) {      // gather1 -> Abuf (bf16, ReLU)
    gatherS<true, true>(p, p.Hbuf, p.b1, (void*)p.Abuf, blockIdx.x);
}
__global__ __launch_bounds__(256, 4) void k_b5(Params p) {   // GEMM2 (dinv, Abuf -> Hs2=Hbuf)
    __shared__ __align__(16) char arena[64 * 136 * 2];
    mfma_sc<true, false>((unsigned short*)arena, p, (const void*)p.Abuf, p.Wt2, p.Hbuf, p.N, blockIdx.x);
}
__global__ __launch_bounds__(256) void k_b6(Params p) {      // gather2 -> out fp32
    gatherS<false, false>(p, p.Hbuf, p.b2, (void*)p.out, blockIdx.x);
}

extern "C" void kernel_launch(void* const* d_in, const int* in_sizes, int n_in,
                              void* d_out, int out_size, void* d_ws, size_t ws_size,
                              hipStream_t stream) {
    Params p;
    p.x  = (const float*)d_in[0];
    p.ei = (const int*)d_in[1];
    p.ew = (const float*)d_in[2];
    p.W1 = (const float*)d_in[3];
    p.b1 = (const float*)d_in[4];
    p.W2 = (const float*)d_in[5];
    p.b2 = (const float*)d_in[6];
    p.out = (float*)d_out;

    p.N = in_sizes[0] / D;
    p.E = in_sizes[2];
    p.C = (p.N + CSZ - 1) / CSZ;
    p.B2n = (p.E + EPB2 - 1) / EPB2;
    p.gb = (p.N + 63) / 64;
    p.hb = (p.N + 15) / 16;

    char* w = (char*)d_ws;
    auto alloc = [&](size_t bytes) {
        void* r = (void*)w;
        w += (bytes + 255) & ~(size_t)255;
        return r;
    };
    // ctot and deg adjacent -> single memset covers both
    p.ctot     = (unsigned int*)alloc((size_t)p.C * 4);
    p.deg      = (float*)alloc((size_t)p.N * 4);
    p.cbase    = (int*)alloc((size_t)(p.C + 1) * 4);
    p.gcur     = (unsigned int*)alloc((size_t)p.C * 4);
    p.dinv     = (float*)alloc((size_t)p.N * 4);
    p.cnt      = (int*)alloc((size_t)p.N * 4);
    p.rowstart = (int*)alloc((size_t)p.N * 4);
    p.brec     = (int2*)alloc((size_t)p.E * 8);
    p.erec     = (int2*)alloc((size_t)p.E * 8);
    p.Hbuf     = (unsigned short*)alloc((size_t)p.N * D * 2);
    p.Abuf     = (unsigned short*)alloc((size_t)p.N * D * 2);
    p.Wt1      = (unsigned short*)alloc(128 * 128 * 2);
    p.Wt2      = (unsigned short*)alloc(128 * 128 * 2);

    size_t zspan = (size_t)((char*)p.deg - (char*)p.ctot) + (size_t)p.N * 4;
    hipMemsetAsync(p.ctot, 0, zspan, stream);

    k_b0<<<2 + p.B2n, 256, 0, stream>>>(p);
    k_b1<<<p.gb + 1, 256, 0, stream>>>(p);
    k_b2<<<p.B2n, 256, 0, stream>>>(p);
    k_b3<<<p.C, 256, 0, stream>>>(p);
    k_b4<<<p.hb, 256, 0, stream>>>(p);
    k_b5<<<p.gb, 256, 0, stream>>>(p);
    k_b6<<<p.hb, 256, 0, stream>>>(p);
}